// Round 10
// baseline (1245.195 us; speedup 1.0000x reference)
//
#include <hip/hip_runtime.h>

// ShootingBlock: only the u-trajectory is observable (traj records y[2K:];
// du = relu(u)@theta^T + bias is self-contained; Mbar/Mbar_b are identity).
//
// R16 (post-mortem of R15, 679us fused): R15 proved fused correctness but
// paid (a) vmcnt(0)-per-phase serialization (~2550cyc/phase vs ~900 ideal)
// and (b) 3.15e7 LDS conflicts from the R6 quad-swizzle theta reads.
// Theta L2 floor for 16-row tiles is ~223us (7.7GB @ 34.5TB/s) - 16 rows
// is forced (fusion pins block count = M/rows; fewer blocks idle CUs).
// R16 = R15 structure + two proven fixes:
//   * fragment-major lane-order theta (R8-proven): phase = 24KB = 24 x 1KB
//     chunks, chunk (split,rowgroup) = one B-fragment in lane order; DMA
//     dest linear (wave-uniform + lane*16), per-lane GLOBAL source carries
//     the permutation; reads contiguous 1KB/wave -> ZERO bv conflicts.
//   * triple-buffered phases + counted vmcnt (R14-proven): distance-2
//     prefetch, per phase {vmcnt(3) -> s_barrier -> dma(phase+2)}, vmcnt(0)
//     only at the very end. Pipeline runs ACROSS feval boundaries (theta is
//     the same every feval); boundary barrier drains lgkm only (A publish).
// Numerics identical to R15 -> absmax bit-identical 4.835703e+24.

namespace {

constexpr int KP = 1024;
constexpr int D  = 512;
constexpr int M  = 4096;

typedef __attribute__((ext_vector_type(8))) short short8;   // 8 bf16 (4 VGPRs)
typedef __attribute__((ext_vector_type(4))) float f32x4;

__device__ __forceinline__ unsigned short f2bf(float f) {  // RNE
  unsigned int u = __float_as_uint(f);
  u += 0x7FFF + ((u >> 16) & 1);
  return (unsigned short)(u >> 16);
}
__device__ __forceinline__ float bf2f(unsigned short h) {
  return __uint_as_float(((unsigned int)h) << 16);
}

__device__ __forceinline__ void glds16(const unsigned short* g, unsigned short* l) {
  __builtin_amdgcn_global_load_lds(
      (__attribute__((address_space(1))) const void*)g,
      (__attribute__((address_space(3))) void*)l, 16, 0, 0);
}

// ---------------------------------------------------------------------------
// part[z][d][e] = sum_{k in chunk z} ps[k][d] * relu(xs[k][e])   (std layout)
// ---------------------------------------------------------------------------
constexpr int KSPLIT = 8;

__global__ __launch_bounds__(256) void theta_partial_kernel(
    const float* __restrict__ xs, const float* __restrict__ ps,
    float* __restrict__ part) {
  __shared__ float As[32][68];  // ps, d-block
  __shared__ float Bs[32][68];  // relu(xs), e-block
  const int d0 = blockIdx.x * 64;
  const int e0 = blockIdx.y * 64;
  const int kb = blockIdx.z * (KP / KSPLIT);
  const int t  = threadIdx.x;
  const int tx = t & 15, ty = t >> 4;
  float acc[4][4] = {};

  for (int k0 = kb; k0 < kb + KP / KSPLIT; k0 += 32) {
#pragma unroll
    for (int p = 0; p < 2; ++p) {
      const int idx = t + p * 256;
      const int c4  = idx & 15;
      const int row = idx >> 4;
      const float4 av = *(const float4*)(ps + (size_t)(k0 + row) * D + d0 + c4 * 4);
      *(float4*)&As[row][c4 * 4] = av;
      float4 bv = *(const float4*)(xs + (size_t)(k0 + row) * D + e0 + c4 * 4);
      bv.x = fmaxf(bv.x, 0.f); bv.y = fmaxf(bv.y, 0.f);
      bv.z = fmaxf(bv.z, 0.f); bv.w = fmaxf(bv.w, 0.f);
      *(float4*)&Bs[row][c4 * 4] = bv;
    }
    __syncthreads();
#pragma unroll
    for (int kk = 0; kk < 32; ++kk) {
      const float4 a4 = *(const float4*)&As[kk][ty * 4];
      const float4 b4 = *(const float4*)&Bs[kk][tx * 4];
      const float a[4] = {a4.x, a4.y, a4.z, a4.w};
      const float b[4] = {b4.x, b4.y, b4.z, b4.w};
#pragma unroll
      for (int i = 0; i < 4; ++i)
#pragma unroll
        for (int j = 0; j < 4; ++j)
          acc[i][j] = fmaf(a[i], b[j], acc[i][j]);
    }
    __syncthreads();
  }
  float* dst = part + (size_t)blockIdx.z * D * D;
#pragma unroll
  for (int i = 0; i < 4; ++i) {
    float4 v;
    v.x = acc[i][0]; v.y = acc[i][1]; v.z = acc[i][2]; v.w = acc[i][3];
    *(float4*)(dst + (size_t)(d0 + ty * 4 + i) * D + e0 + tx * 4) = v;
  }
}

// theta = -(sum partials); split-3 into bf16 arrays th0,th1,th2 [d][e]
__global__ __launch_bounds__(256) void theta_combine_kernel(
    const float* __restrict__ part, unsigned short* __restrict__ th0,
    unsigned short* __restrict__ th1, unsigned short* __restrict__ th2) {
  const size_t i = (size_t)blockIdx.x * 256 + threadIdx.x;  // float4 index
  float4 s = ((const float4*)part)[i];
#pragma unroll
  for (int z = 1; z < KSPLIT; ++z) {
    const float4 v = ((const float4*)(part + (size_t)z * D * D))[i];
    s.x += v.x; s.y += v.y; s.z += v.z; s.w += v.w;
  }
  const float vv[4] = {-s.x, -s.y, -s.z, -s.w};
  ushort4 h0, h1, h2;
  unsigned short* p0[4] = {&h0.x, &h0.y, &h0.z, &h0.w};
  unsigned short* p1[4] = {&h1.x, &h1.y, &h1.z, &h1.w};
  unsigned short* p2[4] = {&h2.x, &h2.y, &h2.z, &h2.w};
#pragma unroll
  for (int c = 0; c < 4; ++c) {
    const float v = vv[c];
    const unsigned short a0 = f2bf(v);
    const float r1 = v - bf2f(a0);
    const unsigned short a1 = f2bf(r1);
    const float r2 = r1 - bf2f(a1);
    *p0[c] = a0; *p1[c] = a1; *p2[c] = f2bf(r2);
  }
  ((ushort4*)th0)[i] = h0;
  ((ushort4*)th1)[i] = h1;
  ((ushort4*)th2)[i] = h2;
}

__global__ __launch_bounds__(256) void bias_kernel(const float* __restrict__ ps,
                                                   float* __restrict__ bias) {
  __shared__ float part[4][64];
  const int dc = threadIdx.x & 63;
  const int sl = threadIdx.x >> 6;
  const int d  = blockIdx.x * 64 + dc;
  float s = 0.f;
  for (int k = sl * 256; k < sl * 256 + 256; ++k) s += ps[(size_t)k * D + d];
  part[sl][dc] = s;
  __syncthreads();
  if (threadIdx.x < 64) {
    const int c = threadIdx.x;
    bias[blockIdx.x * 64 + c] =
        -(part[0][c] + part[1][c] + part[2][c] + part[3][c]);
  }
}

// ---------------------------------------------------------------------------
// Fused RK4: block = 16 m-rows x 512 n. 512 thr = 8 waves; per phase
// (es, nq): theta n-rows [nq*128, nq*128+128), wave w owns rowgroup w
// (n = nq*128 + w*16 + nl). Thread outputs: (m = m0+qq*4+r, n as above),
// nq 0..3, r 0..3 -> 16 f32. Theta phases: 24KB = 24 lane-order 1KB
// fragment chunks, triple-buffered, distance-2 counted-vmcnt prefetch.
// A = split3(relu(y)) in LDS [3][16][516], rebuilt per stage.
// ---------------------------------------------------------------------------
__global__ __launch_bounds__(512, 1) void fused_rk4_kernel(
    const float* __restrict__ inp, const unsigned short* __restrict__ th0,
    const unsigned short* __restrict__ th1, const unsigned short* __restrict__ th2,
    const float* __restrict__ bias, const float* __restrict__ bt,
    float* __restrict__ out) {
  __shared__ unsigned short A_lds[3 * 16 * 516];   // 49,536 B
  __shared__ unsigned short T_lds[3 * 24 * 512];   // 73,728 B (3 phase bufs)
  const int t    = threadIdx.x;
  const int w    = t >> 6;         // wave 0..7
  const int lane = t & 63;
  const int nl   = lane & 15;
  const int qq   = lane >> 4;
  const int m0   = blockIdx.x * 16;
  const unsigned short* Tarr[3] = {th0, th1, th2};

  // Per-lane theta sources for this wave's 3 chunks. Chunk c = w*3+j in
  // [0,24): split s = c>>3, rowgroup rg = c&7. Lane p of chunk holds
  // row rg*16+(p&15), k (p>>4)*8 -> source offset (rg*16+nl)*D + qq*8.
  const unsigned short* tsrc[3];
  int tdst[3];
#pragma unroll
  for (int j = 0; j < 3; ++j) {
    const int c  = w * 3 + j;
    const int s  = c >> 3;
    const int rg = c & 7;
    tsrc[j] = Tarr[s] + (size_t)(rg * 16 + nl) * D + qq * 8;
    tdst[j] = c * 512;   // ushort offset of chunk (1KB each)
  }
  auto dmaT = [&](int buf, int es, int nq) {
#pragma unroll
    for (int j = 0; j < 3; ++j)
      glds16(tsrc[j] + (size_t)nq * 128 * D + es * 32,
             &T_lds[buf * 12288 + tdst[j]]);
  };

  // Build A = split3(relu(v)) into LDS [s][m][e], pitch 516.
  auto buildA = [&](const float (&v)[4][4]) {
#pragma unroll
    for (int nq = 0; nq < 4; ++nq)
#pragma unroll
      for (int r = 0; r < 4; ++r) {
        const float ry = fmaxf(v[nq][r], 0.f);
        const unsigned short a0 = f2bf(ry);
        const float r1 = ry - bf2f(a0);
        const unsigned short a1 = f2bf(r1);
        const unsigned short a2 = f2bf(r1 - bf2f(a1));
        const int idx = (qq * 4 + r) * 516 + nq * 128 + w * 16 + nl;
        A_lds[idx]         = a0;
        A_lds[8256 + idx]  = a1;
        A_lds[16512 + idx] = a2;
      }
  };

  float u[4][4], ra[4][4], bb[4];
#pragma unroll
  for (int nq = 0; nq < 4; ++nq) {
    const int n = nq * 128 + w * 16 + nl;
    bb[nq] = bias[n];
#pragma unroll
    for (int r = 0; r < 4; ++r) {
      const size_t off = (size_t)(m0 + qq * 4 + r) * D + n;
      const float v = inp[off];
      u[nq][r]  = v;
      ra[nq][r] = 0.f;
      out[off]  = v;                       // out[0] = inp
    }
  }

  // Prologue: issue phases 0,1; build A; publish A (lgkm-only barrier so
  // the DMA queue survives).
  dmaT(0, 0, 0);
  dmaT(1, 0, 1);
  buildA(u);
  asm volatile("s_waitcnt lgkmcnt(0)" ::: "memory");
  __builtin_amdgcn_sched_barrier(0);
  __builtin_amdgcn_s_barrier();
  __builtin_amdgcn_sched_barrier(0);

  int bufc = 0;  // buffer of the current phase (global phase % 3)

  for (int g = 0; g < 20; ++g) {
    f32x4 C[4];
#pragma unroll
    for (int nq = 0; nq < 4; ++nq) C[nq] = (f32x4){0.f, 0.f, 0.f, 0.f};
    short8 av[3];

    for (int es = 0; es < 16; ++es) {
#pragma unroll
      for (int nq = 0; nq < 4; ++nq) {
        // Counted wait: this phase's 3 DMAs are the oldest of 6 outstanding.
        if (g == 19 && es == 15 && nq == 3) {
          asm volatile("s_waitcnt vmcnt(0)" ::: "memory");
        } else {
          asm volatile("s_waitcnt vmcnt(3)" ::: "memory");
        }
        __builtin_amdgcn_sched_barrier(0);
        __builtin_amdgcn_s_barrier();
        __builtin_amdgcn_sched_barrier(0);

        // Prefetch phase+2 (wraps into the next feval: same theta data).
        {
          const int p = es * 4 + nq + 2;          // 2..65
          if (!(g == 19 && p >= 64)) {
            const int pm = p & 63;
            int pb = bufc + 2; if (pb >= 3) pb -= 3;
            dmaT(pb, pm >> 2, pm & 3);
          }
        }

        if (nq == 0) {
#pragma unroll
          for (int s = 0; s < 3; ++s)
            av[s] = *(const short8*)&A_lds[s * 8256 + nl * 516 + es * 32 + qq * 8];
        }
        short8 bv[3];
#pragma unroll
        for (int s = 0; s < 3; ++s)
          bv[s] = *(const short8*)&T_lds[bufc * 12288 + (s * 8 + w) * 512 + lane * 8];

        f32x4 c = C[nq];
        c = __builtin_amdgcn_mfma_f32_16x16x32_bf16(av[0], bv[0], c, 0, 0, 0);
        c = __builtin_amdgcn_mfma_f32_16x16x32_bf16(av[0], bv[1], c, 0, 0, 0);
        c = __builtin_amdgcn_mfma_f32_16x16x32_bf16(av[1], bv[0], c, 0, 0, 0);
        c = __builtin_amdgcn_mfma_f32_16x16x32_bf16(av[0], bv[2], c, 0, 0, 0);
        c = __builtin_amdgcn_mfma_f32_16x16x32_bf16(av[1], bv[1], c, 0, 0, 0);
        c = __builtin_amdgcn_mfma_f32_16x16x32_bf16(av[2], bv[0], c, 0, 0, 0);
        C[nq] = c;

        bufc = (bufc == 2) ? 0 : bufc + 1;
      }
    }

    // ---- feval epilogue: RK4 state entirely in registers ------------------
    const int st = g >> 2;
    const float dt = bt[st + 1] - bt[st];
    const int md = g & 3;
    const float cn = (md == 2) ? dt : 0.5f * dt;
    const float s6 = dt * (1.f / 6.f);
    float y[4][4];
#pragma unroll
    for (int nq = 0; nq < 4; ++nq)
#pragma unroll
      for (int r = 0; r < 4; ++r) {
        const float kv = C[nq][r] + bb[nq];
        if (md == 0) {
          ra[nq][r] = kv;
          y[nq][r] = fmaf(cn, kv, u[nq][r]);
        } else if (md <= 2) {
          ra[nq][r] = fmaf(2.f, kv, ra[nq][r]);
          y[nq][r] = fmaf(cn, kv, u[nq][r]);
        } else {
          const float yy = fmaf(s6, ra[nq][r] + kv, u[nq][r]);
          y[nq][r] = yy;
          u[nq][r] = yy;
          out[(size_t)(st + 1) * M * D +
              (size_t)(m0 + qq * 4 + r) * D + nq * 128 + w * 16 + nl] = yy;
        }
      }
    if (g < 19) {
      // Rebuild A; lgkm-only barrier preserves the in-flight theta DMAs.
      // Safety: every wave's last A-read (phase es=15,nq=0) retired before
      // it passed barrier (15,1) (lgkm waits precede the consuming MFMAs),
      // and buildA runs after all barriers of this feval.
      buildA(y);
      asm volatile("s_waitcnt lgkmcnt(0)" ::: "memory");
      __builtin_amdgcn_sched_barrier(0);
      __builtin_amdgcn_s_barrier();
      __builtin_amdgcn_sched_barrier(0);
    }
  }
}

}  // namespace

extern "C" void kernel_launch(void* const* d_in, const int* in_sizes, int n_in,
                              void* d_out, int out_size, void* d_ws, size_t ws_size,
                              hipStream_t stream) {
  (void)in_sizes; (void)n_in; (void)out_size; (void)ws_size;
  const float* xs  = (const float*)d_in[0];  // x_params (K,1,D)
  const float* ps  = (const float*)d_in[1];  // p_params (K,1,D)
  // d_in[2] Mbar, d_in[3] Mbar_b: identity -> inv() no-op
  const float* inp = (const float*)d_in[4];  // (M,1,D)
  const float* bt  = (const float*)d_in[5];  // (T,)
  float* out = (float*)d_out;                // (T, M, 1, D)
  float* ws  = (float*)d_ws;

  float* part = ws;                           // KSPLIT*D*D floats (8 MB)
  float* bias = part + (size_t)M * D;         // 512
  unsigned short* th0 = (unsigned short*)(bias + 512);   // D*D bf16 each
  unsigned short* th1 = th0 + (size_t)D * D;
  unsigned short* th2 = th1 + (size_t)D * D;

  theta_partial_kernel<<<dim3(8, 8, KSPLIT), 256, 0, stream>>>(xs, ps, part);
  theta_combine_kernel<<<(D * D) / (4 * 256), 256, 0, stream>>>(part, th0, th1, th2);
  bias_kernel<<<D / 64, 256, 0, stream>>>(ps, bias);

  fused_rk4_kernel<<<M / 16, 512, 0, stream>>>(inp, th0, th1, th2, bias, bt, out);
}

// Round 11
// 967.383 us; speedup vs baseline: 1.2872x; 1.2872x over previous
//
#include <hip/hip_runtime.h>

// ShootingBlock: only the u-trajectory is observable (traj records y[2K:];
// du = relu(u)@theta^T + bias is self-contained; Mbar/Mbar_b are identity).
//
// R17 (post-mortem of R14/R15/R16): per-barrier-phase cost is ~1us
// REGARDLESS of phase size (R14 1.13, R15 1.06, R16 0.94) -> the lockstep
// {vmcnt -> s_barrier} per phase is the bottleneck, not BW/conflicts.
// Fix: theta phases need NO cross-wave sharing (each wave consumes a
// disjoint n-slice). Wave-private streaming, ZERO per-phase barriers:
//   * wave w owns n in {w*32..+32} and {256+w*32..+32} (R15 ownership).
//     Per phase (es,h): 6KB = 6 lane-order 1KB chunks (R16-proven
//     conflict-free fragment-major layout) into a PRIVATE 2x6KB ring.
//   * self-paced counted vmcnt(6): wait(p) -> compute(p) -> issue(p+2)
//     into the same buffer (reuse-after-read = distance-2 with 2 bufs).
//     Waves free-run; 2 waves/SIMD interleave (TLP) -- barriers forbade.
//   * 2 barriers per feval (A-read-done, A-publish) = 40 total vs 1280.
//     Epilogue stores enter vmcnt but only cause over-wait (oldest-first).
// LDS: A 49.5KB + 8 x 12KB = 145.5KB, 1 block/CU, 8 waves.
// Epilogue/buildA/ownership R15-verbatim -> absmax bit-identical
// 4.835703e+24.

namespace {

constexpr int KP = 1024;
constexpr int D  = 512;
constexpr int M  = 4096;

typedef __attribute__((ext_vector_type(8))) short short8;   // 8 bf16 (4 VGPRs)
typedef __attribute__((ext_vector_type(4))) float f32x4;

__device__ __forceinline__ unsigned short f2bf(float f) {  // RNE
  unsigned int u = __float_as_uint(f);
  u += 0x7FFF + ((u >> 16) & 1);
  return (unsigned short)(u >> 16);
}
__device__ __forceinline__ float bf2f(unsigned short h) {
  return __uint_as_float(((unsigned int)h) << 16);
}

__device__ __forceinline__ void glds16(const unsigned short* g, unsigned short* l) {
  __builtin_amdgcn_global_load_lds(
      (__attribute__((address_space(1))) const void*)g,
      (__attribute__((address_space(3))) void*)l, 16, 0, 0);
}

// ---------------------------------------------------------------------------
// part[z][d][e] = sum_{k in chunk z} ps[k][d] * relu(xs[k][e])   (std layout)
// ---------------------------------------------------------------------------
constexpr int KSPLIT = 8;

__global__ __launch_bounds__(256) void theta_partial_kernel(
    const float* __restrict__ xs, const float* __restrict__ ps,
    float* __restrict__ part) {
  __shared__ float As[32][68];  // ps, d-block
  __shared__ float Bs[32][68];  // relu(xs), e-block
  const int d0 = blockIdx.x * 64;
  const int e0 = blockIdx.y * 64;
  const int kb = blockIdx.z * (KP / KSPLIT);
  const int t  = threadIdx.x;
  const int tx = t & 15, ty = t >> 4;
  float acc[4][4] = {};

  for (int k0 = kb; k0 < kb + KP / KSPLIT; k0 += 32) {
#pragma unroll
    for (int p = 0; p < 2; ++p) {
      const int idx = t + p * 256;
      const int c4  = idx & 15;
      const int row = idx >> 4;
      const float4 av = *(const float4*)(ps + (size_t)(k0 + row) * D + d0 + c4 * 4);
      *(float4*)&As[row][c4 * 4] = av;
      float4 bv = *(const float4*)(xs + (size_t)(k0 + row) * D + e0 + c4 * 4);
      bv.x = fmaxf(bv.x, 0.f); bv.y = fmaxf(bv.y, 0.f);
      bv.z = fmaxf(bv.z, 0.f); bv.w = fmaxf(bv.w, 0.f);
      *(float4*)&Bs[row][c4 * 4] = bv;
    }
    __syncthreads();
#pragma unroll
    for (int kk = 0; kk < 32; ++kk) {
      const float4 a4 = *(const float4*)&As[kk][ty * 4];
      const float4 b4 = *(const float4*)&Bs[kk][tx * 4];
      const float a[4] = {a4.x, a4.y, a4.z, a4.w};
      const float b[4] = {b4.x, b4.y, b4.z, b4.w};
#pragma unroll
      for (int i = 0; i < 4; ++i)
#pragma unroll
        for (int j = 0; j < 4; ++j)
          acc[i][j] = fmaf(a[i], b[j], acc[i][j]);
    }
    __syncthreads();
  }
  float* dst = part + (size_t)blockIdx.z * D * D;
#pragma unroll
  for (int i = 0; i < 4; ++i) {
    float4 v;
    v.x = acc[i][0]; v.y = acc[i][1]; v.z = acc[i][2]; v.w = acc[i][3];
    *(float4*)(dst + (size_t)(d0 + ty * 4 + i) * D + e0 + tx * 4) = v;
  }
}

// theta = -(sum partials); split-3 into bf16 arrays th0,th1,th2 [d][e]
__global__ __launch_bounds__(256) void theta_combine_kernel(
    const float* __restrict__ part, unsigned short* __restrict__ th0,
    unsigned short* __restrict__ th1, unsigned short* __restrict__ th2) {
  const size_t i = (size_t)blockIdx.x * 256 + threadIdx.x;  // float4 index
  float4 s = ((const float4*)part)[i];
#pragma unroll
  for (int z = 1; z < KSPLIT; ++z) {
    const float4 v = ((const float4*)(part + (size_t)z * D * D))[i];
    s.x += v.x; s.y += v.y; s.z += v.z; s.w += v.w;
  }
  const float vv[4] = {-s.x, -s.y, -s.z, -s.w};
  ushort4 h0, h1, h2;
  unsigned short* p0[4] = {&h0.x, &h0.y, &h0.z, &h0.w};
  unsigned short* p1[4] = {&h1.x, &h1.y, &h1.z, &h1.w};
  unsigned short* p2[4] = {&h2.x, &h2.y, &h2.z, &h2.w};
#pragma unroll
  for (int c = 0; c < 4; ++c) {
    const float v = vv[c];
    const unsigned short a0 = f2bf(v);
    const float r1 = v - bf2f(a0);
    const unsigned short a1 = f2bf(r1);
    const float r2 = r1 - bf2f(a1);
    *p0[c] = a0; *p1[c] = a1; *p2[c] = f2bf(r2);
  }
  ((ushort4*)th0)[i] = h0;
  ((ushort4*)th1)[i] = h1;
  ((ushort4*)th2)[i] = h2;
}

__global__ __launch_bounds__(256) void bias_kernel(const float* __restrict__ ps,
                                                   float* __restrict__ bias) {
  __shared__ float part[4][64];
  const int dc = threadIdx.x & 63;
  const int sl = threadIdx.x >> 6;
  const int d  = blockIdx.x * 64 + dc;
  float s = 0.f;
  for (int k = sl * 256; k < sl * 256 + 256; ++k) s += ps[(size_t)k * D + d];
  part[sl][dc] = s;
  __syncthreads();
  if (threadIdx.x < 64) {
    const int c = threadIdx.x;
    bias[blockIdx.x * 64 + c] =
        -(part[0][c] + part[1][c] + part[2][c] + part[3][c]);
  }
}

// ---------------------------------------------------------------------------
// Fused RK4: block = 16 m-rows x 512 n. 512 thr = 8 waves. Thread owns
// (m = m0+qq*4+r, n = h*256 + w*32 + nf*16 + nl), h,nf in {0,1} (R15 map).
// Theta: wave-private ring T_lds[w][buf=h][6 chunks][512]; phase (es,h)
// = 6 lane-order 1KB chunks (chunk j: split s=j>>1, rowgroup rg=j&1; lane p
// holds row rg*16+(p&15), k-quad p>>4). No cross-wave barriers in phases.
// A = split3(relu(y)) in LDS [3][16][516], rebuilt per feval (2 barriers).
// ---------------------------------------------------------------------------
__global__ __launch_bounds__(512, 1) void fused_rk4_kernel(
    const float* __restrict__ inp, const unsigned short* __restrict__ th0,
    const unsigned short* __restrict__ th1, const unsigned short* __restrict__ th2,
    const float* __restrict__ bias, const float* __restrict__ bt,
    float* __restrict__ out) {
  __shared__ unsigned short A_lds[3 * 16 * 516];      // 49,536 B
  __shared__ unsigned short T_lds[8 * 2 * 6 * 512];   // 98,304 B wave-private
  const int t    = threadIdx.x;
  const int w    = t >> 6;         // wave 0..7
  const int lane = t & 63;
  const int nl   = lane & 15;
  const int qq   = lane >> 4;
  const int m0   = blockIdx.x * 16;
  const unsigned short* Tarr[3] = {th0, th1, th2};

  // Wave-private theta DMA: phase (es,h) -> buffer h. Chunk j (j=s*2+rg):
  // per-lane global src (rg*16+nl)*D + qq*8 within the (h,w) row block;
  // LDS dest wave-uniform (HW adds lane*16) -> lane-order fragment chunk.
  unsigned short* tbase[2];
  tbase[0] = &T_lds[(w * 2 + 0) * 3072];
  tbase[1] = &T_lds[(w * 2 + 1) * 3072];
  auto dmaT = [&](int buf, int es, int h) {
    const size_t lanesrc = (size_t)(h * 256 + w * 32 + nl) * D + es * 32 + qq * 8;
#pragma unroll
    for (int j = 0; j < 6; ++j) {
      const int s  = j >> 1;
      const int rg = j & 1;
      glds16(Tarr[s] + lanesrc + (size_t)rg * 16 * D, tbase[buf] + j * 512);
    }
  };

  // Build A = split3(relu(v)) into LDS [s][m][e], pitch 516 (R15 verbatim).
  auto buildA = [&](const float (&v)[2][2][4]) {
#pragma unroll
    for (int h = 0; h < 2; ++h)
#pragma unroll
      for (int nf = 0; nf < 2; ++nf)
#pragma unroll
        for (int r = 0; r < 4; ++r) {
          const float ry = fmaxf(v[h][nf][r], 0.f);
          const unsigned short a0 = f2bf(ry);
          const float r1 = ry - bf2f(a0);
          const unsigned short a1 = f2bf(r1);
          const unsigned short a2 = f2bf(r1 - bf2f(a1));
          const int idx = (qq * 4 + r) * 516 + h * 256 + w * 32 + nf * 16 + nl;
          A_lds[idx]         = a0;
          A_lds[8256 + idx]  = a1;
          A_lds[16512 + idx] = a2;
        }
  };

  float u[2][2][4], ra[2][2][4], bb[2][2];
#pragma unroll
  for (int h = 0; h < 2; ++h)
#pragma unroll
    for (int nf = 0; nf < 2; ++nf) {
      const int n = h * 256 + w * 32 + nf * 16 + nl;
      bb[h][nf] = bias[n];
#pragma unroll
      for (int r = 0; r < 4; ++r) {
        const size_t off = (size_t)(m0 + qq * 4 + r) * D + n;
        const float v = inp[off];
        u[h][nf][r]  = v;
        ra[h][nf][r] = 0.f;
        out[off]     = v;                 // out[0] = inp
      }
    }

  // Prologue: phases (0,0),(0,1) in flight; build+publish A.
  dmaT(0, 0, 0);
  dmaT(1, 0, 1);
  buildA(u);
  asm volatile("s_waitcnt lgkmcnt(0)" ::: "memory");
  __builtin_amdgcn_sched_barrier(0);
  __builtin_amdgcn_s_barrier();
  __builtin_amdgcn_sched_barrier(0);

  for (int g = 0; g < 20; ++g) {
    f32x4 C[2][2];
#pragma unroll
    for (int h = 0; h < 2; ++h)
#pragma unroll
      for (int nf = 0; nf < 2; ++nf) C[h][nf] = (f32x4){0.f, 0.f, 0.f, 0.f};
    short8 av[3];

    for (int es = 0; es < 16; ++es) {
#pragma unroll
      for (int h = 0; h < 2; ++h) {
        const int p = es * 2 + h;           // phase 0..31, buffer = h
        // Self-paced counted wait: this phase's 6 DMAs are the oldest.
        // (Epilogue stores/inp loads only cause over-wait: oldest-first.)
        if (g == 19 && p == 31) {
          asm volatile("s_waitcnt vmcnt(0)" ::: "memory");
        } else {
          asm volatile("s_waitcnt vmcnt(6)" ::: "memory");
        }
        __builtin_amdgcn_sched_barrier(0);

        if (h == 0) {
#pragma unroll
          for (int s = 0; s < 3; ++s)
            av[s] = *(const short8*)&A_lds[s * 8256 + nl * 516 + es * 32 + qq * 8];
        }
        short8 bv[2][3];
#pragma unroll
        for (int nf = 0; nf < 2; ++nf)
#pragma unroll
          for (int s = 0; s < 3; ++s)
            bv[nf][s] = *(const short8*)(tbase[h] + (s * 2 + nf) * 512 + lane * 8);
#pragma unroll
        for (int nf = 0; nf < 2; ++nf) {
          f32x4 c = C[h][nf];
          c = __builtin_amdgcn_mfma_f32_16x16x32_bf16(av[0], bv[nf][0], c, 0, 0, 0);
          c = __builtin_amdgcn_mfma_f32_16x16x32_bf16(av[0], bv[nf][1], c, 0, 0, 0);
          c = __builtin_amdgcn_mfma_f32_16x16x32_bf16(av[1], bv[nf][0], c, 0, 0, 0);
          c = __builtin_amdgcn_mfma_f32_16x16x32_bf16(av[0], bv[nf][2], c, 0, 0, 0);
          c = __builtin_amdgcn_mfma_f32_16x16x32_bf16(av[1], bv[nf][1], c, 0, 0, 0);
          c = __builtin_amdgcn_mfma_f32_16x16x32_bf16(av[2], bv[nf][0], c, 0, 0, 0);
          C[h][nf] = c;
        }
        // bv consumed (ds_reads retired via MFMA's lgkm waits); make it
        // explicit, then refill THIS buffer for phase p+2 (same h, es+1).
        asm volatile("s_waitcnt lgkmcnt(0)" ::: "memory");
        __builtin_amdgcn_sched_barrier(0);
        if (!(g == 19 && p >= 30)) dmaT(h, (es + 1) & 15, h);
      }
    }

    // ---- feval epilogue: RK4 state entirely in registers (R15 verbatim) --
    const int st = g >> 2;
    const float dt = bt[st + 1] - bt[st];
    const int md = g & 3;
    const float cn = (md == 2) ? dt : 0.5f * dt;
    const float s6 = dt * (1.f / 6.f);
    float y[2][2][4];
#pragma unroll
    for (int h = 0; h < 2; ++h)
#pragma unroll
      for (int nf = 0; nf < 2; ++nf)
#pragma unroll
        for (int r = 0; r < 4; ++r) {
          const float kv = C[h][nf][r] + bb[h][nf];
          if (md == 0) {
            ra[h][nf][r] = kv;
            y[h][nf][r] = fmaf(cn, kv, u[h][nf][r]);
          } else if (md <= 2) {
            ra[h][nf][r] = fmaf(2.f, kv, ra[h][nf][r]);
            y[h][nf][r] = fmaf(cn, kv, u[h][nf][r]);
          } else {
            const float yy = fmaf(s6, ra[h][nf][r] + kv, u[h][nf][r]);
            y[h][nf][r] = yy;
            u[h][nf][r] = yy;
            out[(size_t)(st + 1) * M * D +
                (size_t)(m0 + qq * 4 + r) * D + h * 256 + w * 32 + nf * 16 + nl] = yy;
          }
        }
    if (g < 19) {
      // Barrier 1: all waves' A-reads retired (values consumed by MFMAs
      // before each wave reached here). Then rebuild + publish (barrier 2).
      // Raw barriers + lgkm-only waits keep the theta DMA queue alive.
      __builtin_amdgcn_s_barrier();
      buildA(y);
      asm volatile("s_waitcnt lgkmcnt(0)" ::: "memory");
      __builtin_amdgcn_sched_barrier(0);
      __builtin_amdgcn_s_barrier();
      __builtin_amdgcn_sched_barrier(0);
    }
  }
}

}  // namespace

extern "C" void kernel_launch(void* const* d_in, const int* in_sizes, int n_in,
                              void* d_out, int out_size, void* d_ws, size_t ws_size,
                              hipStream_t stream) {
  (void)in_sizes; (void)n_in; (void)out_size; (void)ws_size;
  const float* xs  = (const float*)d_in[0];  // x_params (K,1,D)
  const float* ps  = (const float*)d_in[1];  // p_params (K,1,D)
  // d_in[2] Mbar, d_in[3] Mbar_b: identity -> inv() no-op
  const float* inp = (const float*)d_in[4];  // (M,1,D)
  const float* bt  = (const float*)d_in[5];  // (T,)
  float* out = (float*)d_out;                // (T, M, 1, D)
  float* ws  = (float*)d_ws;

  float* part = ws;                           // KSPLIT*D*D floats (8 MB)
  float* bias = part + (size_t)M * D;         // 512
  unsigned short* th0 = (unsigned short*)(bias + 512);   // D*D bf16 each
  unsigned short* th1 = th0 + (size_t)D * D;
  unsigned short* th2 = th1 + (size_t)D * D;

  theta_partial_kernel<<<dim3(8, 8, KSPLIT), 256, 0, stream>>>(xs, ps, part);
  theta_combine_kernel<<<(D * D) / (4 * 256), 256, 0, stream>>>(part, th0, th1, th2);
  bias_kernel<<<D / 64, 256, 0, stream>>>(ps, bias);

  fused_rk4_kernel<<<M / 16, 512, 0, stream>>>(inp, th0, th1, th2, bias, bt, out);
}

// Round 12
// 690.212 us; speedup vs baseline: 1.8041x; 1.4016x over previous
//
#include <hip/hip_runtime.h>

// ShootingBlock: only the u-trajectory is observable (traj records y[2K:];
// du = relu(u)@theta^T + bias is self-contained; Mbar/Mbar_b are identity).
//
// R18 (post-mortem of R14..R17): fused-16-row family closed (679/1209/937us
// vs R14 525us; theta-L2 floor ~223us + sync laws keep it >650). Two laws:
// (1) lockstep phases cost ~0.5-0.7us FIXED each (R14 1.13, R15 1.06,
// R16 0.94 us/phase at very different phase sizes); (2) wave-private tiny
// phases are worse (R17 1.46us). So: champion R14 structure, HALVE phases.
//   * 128x64 block, 512 thr = 8 waves (4x2 grid, 32x32 wave tile), 8 slabs
//     of K=64. 2x72KB LDS dbuf (144KB, 1 block/CU -> 8 waves/CU, same
//     occupancy as R14's 2x4-wave blocks).
//   * per slab: {vmcnt(0) -> s_barrier -> dma(next)}: issue-to-wait = one
//     full slab (~2900cy) >> HBM latency -> the drain is free (R6's wasn't
//     because issue was right before the wait). Distance-1 dbuf, race-safe
//     (reads retired before barrier via lgkm-before-MFMA; write issued
//     after barrier).
//   * fragment-major lane-order chunks (R16-proven, conflicts->0) for BOTH
//     A and B: 72 x 1KB chunks, 9 DMAs/wave/slab, reads base+lane*8.
//   * theta L2 traffic halves (32 m-blocks vs 64).
// Numerics identical to R14: same 6 products, same K order, same chains ->
// absmax must be bit-identical 4.835703e+24.

namespace {

constexpr int KP = 1024;
constexpr int D  = 512;
constexpr int M  = 4096;

typedef __attribute__((ext_vector_type(8))) short short8;   // 8 bf16 (4 VGPRs)
typedef __attribute__((ext_vector_type(4))) float f32x4;

__device__ __forceinline__ unsigned short f2bf(float f) {  // RNE
  unsigned int u = __float_as_uint(f);
  u += 0x7FFF + ((u >> 16) & 1);
  return (unsigned short)(u >> 16);
}
__device__ __forceinline__ float bf2f(unsigned short h) {
  return __uint_as_float(((unsigned int)h) << 16);
}

__device__ __forceinline__ void glds16(const unsigned short* g, unsigned short* l) {
  __builtin_amdgcn_global_load_lds(
      (__attribute__((address_space(1))) const void*)g,
      (__attribute__((address_space(3))) void*)l, 16, 0, 0);
}

// ---------------------------------------------------------------------------
// part[z][d][e] = sum_{k in chunk z} ps[k][d] * relu(xs[k][e])   (std layout)
// ---------------------------------------------------------------------------
constexpr int KSPLIT = 8;

__global__ __launch_bounds__(256) void theta_partial_kernel(
    const float* __restrict__ xs, const float* __restrict__ ps,
    float* __restrict__ part) {
  __shared__ float As[32][68];  // ps, d-block
  __shared__ float Bs[32][68];  // relu(xs), e-block
  const int d0 = blockIdx.x * 64;
  const int e0 = blockIdx.y * 64;
  const int kb = blockIdx.z * (KP / KSPLIT);
  const int t  = threadIdx.x;
  const int tx = t & 15, ty = t >> 4;
  float acc[4][4] = {};

  for (int k0 = kb; k0 < kb + KP / KSPLIT; k0 += 32) {
#pragma unroll
    for (int p = 0; p < 2; ++p) {
      const int idx = t + p * 256;
      const int c4  = idx & 15;
      const int row = idx >> 4;
      const float4 av = *(const float4*)(ps + (size_t)(k0 + row) * D + d0 + c4 * 4);
      *(float4*)&As[row][c4 * 4] = av;
      float4 bv = *(const float4*)(xs + (size_t)(k0 + row) * D + e0 + c4 * 4);
      bv.x = fmaxf(bv.x, 0.f); bv.y = fmaxf(bv.y, 0.f);
      bv.z = fmaxf(bv.z, 0.f); bv.w = fmaxf(bv.w, 0.f);
      *(float4*)&Bs[row][c4 * 4] = bv;
    }
    __syncthreads();
#pragma unroll
    for (int kk = 0; kk < 32; ++kk) {
      const float4 a4 = *(const float4*)&As[kk][ty * 4];
      const float4 b4 = *(const float4*)&Bs[kk][tx * 4];
      const float a[4] = {a4.x, a4.y, a4.z, a4.w};
      const float b[4] = {b4.x, b4.y, b4.z, b4.w};
#pragma unroll
      for (int i = 0; i < 4; ++i)
#pragma unroll
        for (int j = 0; j < 4; ++j)
          acc[i][j] = fmaf(a[i], b[j], acc[i][j]);
    }
    __syncthreads();
  }
  float* dst = part + (size_t)blockIdx.z * D * D;
#pragma unroll
  for (int i = 0; i < 4; ++i) {
    float4 v;
    v.x = acc[i][0]; v.y = acc[i][1]; v.z = acc[i][2]; v.w = acc[i][3];
    *(float4*)(dst + (size_t)(d0 + ty * 4 + i) * D + e0 + tx * 4) = v;
  }
}

// theta = -(sum partials); split-3 into bf16 arrays th0,th1,th2 [d][e]
__global__ __launch_bounds__(256) void theta_combine_kernel(
    const float* __restrict__ part, unsigned short* __restrict__ th0,
    unsigned short* __restrict__ th1, unsigned short* __restrict__ th2) {
  const size_t i = (size_t)blockIdx.x * 256 + threadIdx.x;  // float4 index
  float4 s = ((const float4*)part)[i];
#pragma unroll
  for (int z = 1; z < KSPLIT; ++z) {
    const float4 v = ((const float4*)(part + (size_t)z * D * D))[i];
    s.x += v.x; s.y += v.y; s.z += v.z; s.w += v.w;
  }
  const float vv[4] = {-s.x, -s.y, -s.z, -s.w};
  ushort4 h0, h1, h2;
  unsigned short* p0[4] = {&h0.x, &h0.y, &h0.z, &h0.w};
  unsigned short* p1[4] = {&h1.x, &h1.y, &h1.z, &h1.w};
  unsigned short* p2[4] = {&h2.x, &h2.y, &h2.z, &h2.w};
#pragma unroll
  for (int c = 0; c < 4; ++c) {
    const float v = vv[c];
    const unsigned short a0 = f2bf(v);
    const float r1 = v - bf2f(a0);
    const unsigned short a1 = f2bf(r1);
    const float r2 = r1 - bf2f(a1);
    *p0[c] = a0; *p1[c] = a1; *p2[c] = f2bf(r2);
  }
  ((ushort4*)th0)[i] = h0;
  ((ushort4*)th1)[i] = h1;
  ((ushort4*)th2)[i] = h2;
}

__global__ __launch_bounds__(256) void bias_kernel(const float* __restrict__ ps,
                                                   float* __restrict__ bias) {
  __shared__ float part[4][64];
  const int dc = threadIdx.x & 63;
  const int sl = threadIdx.x >> 6;
  const int d  = blockIdx.x * 64 + dc;
  float s = 0.f;
  for (int k = sl * 256; k < sl * 256 + 256; ++k) s += ps[(size_t)k * D + d];
  part[sl][dc] = s;
  __syncthreads();
  if (threadIdx.x < 64) {
    const int c = threadIdx.x;
    bias[blockIdx.x * 64 + c] =
        -(part[0][c] + part[1][c] + part[2][c] + part[3][c]);
  }
}

// out0 = inp; y* = split3(relu(inp)) in [m][e] bf16.
__global__ __launch_bounds__(256) void init_kernel(
    const float* __restrict__ inp, float* __restrict__ out0,
    unsigned short* __restrict__ y0, unsigned short* __restrict__ y1,
    unsigned short* __restrict__ y2) {
  const size_t i = (size_t)blockIdx.x * 256 + threadIdx.x;  // float4 index
  const float4 v = ((const float4*)inp)[i];
  ((float4*)out0)[i] = v;
  const float vv[4] = {fmaxf(v.x, 0.f), fmaxf(v.y, 0.f),
                       fmaxf(v.z, 0.f), fmaxf(v.w, 0.f)};
  ushort4 h0, h1, h2;
  unsigned short* p0[4] = {&h0.x, &h0.y, &h0.z, &h0.w};
  unsigned short* p1[4] = {&h1.x, &h1.y, &h1.z, &h1.w};
  unsigned short* p2[4] = {&h2.x, &h2.y, &h2.z, &h2.w};
#pragma unroll
  for (int c = 0; c < 4; ++c) {
    const unsigned short a0 = f2bf(vv[c]);
    const float r1 = vv[c] - bf2f(a0);
    const unsigned short a1 = f2bf(r1);
    const float r2 = r1 - bf2f(a1);
    *p0[c] = a0; *p1[c] = a1; *p2[c] = f2bf(r2);
  }
  ((ushort4*)y0)[i] = h0;
  ((ushort4*)y1)[i] = h1;
  ((ushort4*)y2)[i] = h2;
}

// ---------------------------------------------------------------------------
// feval<MODE>: k[m][n] = bias[n] + sum_e A[m][e]*theta[n][e], A = split yin.
//  MODE 0: acc = k;   y = u + dt/2 k     MODE 1: acc += 2k;  y = u + dt/2 k
//  MODE 2: acc += 2k; y = u + dt   k     MODE 3: y = u + dt/6 (acc+k) -> out
//
// 128x64 tile, 512 thr = 8 waves, wave w -> 32x32 subtile at
// (wr,wc) = (w>>1, w&1): m-rows [wr*32,+32), n-rows [wc*32,+32).
// LDS T[2][72][512]: slab buffer = 72 lane-order 1KB fragment chunks.
// A chunks [0,48): c = (s*2+kh)*8+rg (rg = m-rowgroup 0..7);
// B chunks [48,72): 48 + (s*2+kh)*4+rg (rg = n-rowgroup 0..3).
// Chunk lane p holds row rg*16+(p&15), k-quad (p>>4) of k-block es*64+kh*32.
// DMA: 9 chunks/wave; per slab {vmcnt(0) -> s_barrier -> dma(next)}.
// ---------------------------------------------------------------------------
template <int MODE>
__global__ __launch_bounds__(512, 1) void feval_kernel(
    const unsigned short* __restrict__ ya0, const unsigned short* __restrict__ ya1,
    const unsigned short* __restrict__ ya2, const unsigned short* __restrict__ th0,
    const unsigned short* __restrict__ th1, const unsigned short* __restrict__ th2,
    const float* __restrict__ bias, const float* __restrict__ bt, int step,
    const float* __restrict__ uStd, float* __restrict__ acc,
    unsigned short* __restrict__ yw0, unsigned short* __restrict__ yw1,
    unsigned short* __restrict__ yw2, float* __restrict__ outStd) {
  __shared__ unsigned short T[2][72][512];  // 144 KB double buffer
  const int t    = threadIdx.x;
  const int w    = t >> 6;
  const int lane = t & 63;
  const int nl   = lane & 15;
  const int qq   = lane >> 4;
  const int wr   = w >> 1;          // m-subtile 0..3
  const int wc   = w & 1;           // n-subtile 0..1
  const int m0   = blockIdx.x * 128;
  const int n0   = blockIdx.y * 64;
  const float dt = bt[step + 1] - bt[step];

  // Per-wave DMA chunk sources (9 chunks). Chunk c = w*9+j; decomposition
  // per header comment. Per-lane source = row (base+rg*16+nl), k kh*32+qq*8.
  const unsigned short* psrc[9];
#pragma unroll
  for (int j = 0; j < 9; ++j) {
    const int c = w * 9 + j;
    if (c < 48) {
      const int s  = c >> 4;
      const int kh = (c >> 3) & 1;
      const int rg = c & 7;
      const unsigned short* ap = (s == 0) ? ya0 : (s == 1) ? ya1 : ya2;
      psrc[j] = ap + (size_t)(m0 + rg * 16 + nl) * D + kh * 32 + qq * 8;
    } else {
      const int cb = c - 48;
      const int s  = cb >> 3;
      const int kh = (cb >> 2) & 1;
      const int rg = cb & 3;
      const unsigned short* bp = (s == 0) ? th0 : (s == 1) ? th1 : th2;
      psrc[j] = bp + (size_t)(n0 + rg * 16 + nl) * D + kh * 32 + qq * 8;
    }
  }

  auto dma = [&](int buf, int es) {
    unsigned short* base = &T[buf][0][0] + (size_t)(w * 9) * 512;
#pragma unroll
    for (int j = 0; j < 9; ++j)
      glds16(psrc[j] + es * 64, base + j * 512);
  };

  float bb[2];
#pragma unroll
  for (int ns = 0; ns < 2; ++ns) bb[ns] = bias[n0 + wc * 32 + ns * 16 + nl];

  f32x4 C[2][2];
#pragma unroll
  for (int ms = 0; ms < 2; ++ms)
#pragma unroll
    for (int ns = 0; ns < 2; ++ns) C[ms][ns] = (f32x4){0.f, 0.f, 0.f, 0.f};

  dma(0, 0);

  for (int es = 0; es < 8; ++es) {
    const int buf = es & 1;
    // Own DMAs issued one full slab ago -> this drain is ~free; barrier
    // then guarantees ALL waves' chunks are staged (each waited on its own).
    asm volatile("s_waitcnt vmcnt(0)" ::: "memory");
    __builtin_amdgcn_sched_barrier(0);
    __builtin_amdgcn_s_barrier();
    __builtin_amdgcn_sched_barrier(0);
    // Refill the other buffer: its readers (slab es-1) all retired their
    // ds_reads before passing the barrier above (lgkm waits precede MFMAs).
    if (es + 1 < 8) dma(buf ^ 1, es + 1);

#pragma unroll
    for (int kh = 0; kh < 2; ++kh) {
      short8 av[2][3], bv[2][3];
#pragma unroll
      for (int ms = 0; ms < 2; ++ms)
#pragma unroll
        for (int s = 0; s < 3; ++s)
          av[ms][s] = *(const short8*)
              &T[buf][(s * 2 + kh) * 8 + wr * 2 + ms][lane * 8];
#pragma unroll
      for (int ns = 0; ns < 2; ++ns)
#pragma unroll
        for (int s = 0; s < 3; ++s)
          bv[ns][s] = *(const short8*)
              &T[buf][48 + (s * 2 + kh) * 4 + wc * 2 + ns][lane * 8];
#pragma unroll
      for (int ms = 0; ms < 2; ++ms)
#pragma unroll
        for (int ns = 0; ns < 2; ++ns) {
          f32x4 c = C[ms][ns];
          c = __builtin_amdgcn_mfma_f32_16x16x32_bf16(av[ms][0], bv[ns][0], c, 0, 0, 0);
          c = __builtin_amdgcn_mfma_f32_16x16x32_bf16(av[ms][0], bv[ns][1], c, 0, 0, 0);
          c = __builtin_amdgcn_mfma_f32_16x16x32_bf16(av[ms][1], bv[ns][0], c, 0, 0, 0);
          c = __builtin_amdgcn_mfma_f32_16x16x32_bf16(av[ms][0], bv[ns][2], c, 0, 0, 0);
          c = __builtin_amdgcn_mfma_f32_16x16x32_bf16(av[ms][1], bv[ns][1], c, 0, 0, 0);
          c = __builtin_amdgcn_mfma_f32_16x16x32_bf16(av[ms][2], bv[ns][0], c, 0, 0, 0);
          C[ms][ns] = c;
        }
    }
  }

  // ---- epilogue: C/D layout col(n)=lane&15, row(m)=(lane>>4)*4+reg ---------
  const float cn = (MODE == 2) ? dt : 0.5f * dt;
  const float s6 = dt * (1.f / 6.f);
#pragma unroll
  for (int ms = 0; ms < 2; ++ms) {
#pragma unroll
    for (int ns = 0; ns < 2; ++ns) {
      const int n = n0 + wc * 32 + ns * 16 + nl;
#pragma unroll
      for (int r = 0; r < 4; ++r) {
        const int m = m0 + wr * 32 + ms * 16 + qq * 4 + r;
        const size_t off = (size_t)m * D + n;
        const float kv = C[ms][ns][r] + bb[ns];
        float y;
        if constexpr (MODE == 0) {
          acc[off] = kv;
          y = fmaf(cn, kv, uStd[off]);
        } else if constexpr (MODE <= 2) {
          const float a = acc[off];
          acc[off] = fmaf(2.f, kv, a);
          y = fmaf(cn, kv, uStd[off]);
        } else {
          const float a = acc[off];
          y = fmaf(s6, a + kv, uStd[off]);
          outStd[off] = y;
        }
        const float ry = fmaxf(y, 0.f);
        const unsigned short h0 = f2bf(ry);
        const float r1 = ry - bf2f(h0);
        const unsigned short h1 = f2bf(r1);
        const float r2 = r1 - bf2f(h1);
        yw0[off] = h0;
        yw1[off] = h1;
        yw2[off] = f2bf(r2);
      }
    }
  }
}

}  // namespace

extern "C" void kernel_launch(void* const* d_in, const int* in_sizes, int n_in,
                              void* d_out, int out_size, void* d_ws, size_t ws_size,
                              hipStream_t stream) {
  (void)in_sizes; (void)n_in; (void)out_size; (void)ws_size;
  const float* xs  = (const float*)d_in[0];  // x_params (K,1,D)
  const float* ps  = (const float*)d_in[1];  // p_params (K,1,D)
  // d_in[2] Mbar, d_in[3] Mbar_b: identity -> inv() no-op
  const float* inp = (const float*)d_in[4];  // (M,1,D)
  const float* bt  = (const float*)d_in[5];  // (T,)
  float* out = (float*)d_out;                // (T, M, 1, D)
  float* ws  = (float*)d_ws;

  float* acc  = ws;                          // M*D floats (8 MB)
  float* bias = acc + (size_t)M * D;         // 512
  unsigned short* th0 = (unsigned short*)(bias + 512);   // D*D bf16 each
  unsigned short* th1 = th0 + (size_t)D * D;
  unsigned short* th2 = th1 + (size_t)D * D;
  unsigned short* ya0 = th2 + (size_t)D * D;             // M*D bf16 each
  unsigned short* ya1 = ya0 + (size_t)M * D;
  unsigned short* ya2 = ya1 + (size_t)M * D;
  unsigned short* yb0 = ya2 + (size_t)M * D;
  unsigned short* yb1 = yb0 + (size_t)M * D;
  unsigned short* yb2 = yb1 + (size_t)M * D;             // total ~34 MB
  float* part = acc;  // theta partials: KSPLIT*D*D = M*D floats exactly

  theta_partial_kernel<<<dim3(8, 8, KSPLIT), 256, 0, stream>>>(xs, ps, part);
  theta_combine_kernel<<<(D * D) / (4 * 256), 256, 0, stream>>>(part, th0, th1, th2);
  bias_kernel<<<D / 64, 256, 0, stream>>>(ps, bias);
  init_kernel<<<(M * D) / (4 * 256), 256, 0, stream>>>(inp, out, ya0, ya1, ya2);

  const dim3 grid(M / 128, D / 64);  // (32, 8) = 256 blocks, 1/CU, 8 waves
  for (int s = 0; s < 5; ++s) {
    float* u     = out + (size_t)s * M * D;
    float* unext = out + (size_t)(s + 1) * M * D;
    feval_kernel<0><<<grid, 512, 0, stream>>>(ya0, ya1, ya2, th0, th1, th2, bias,
                                              bt, s, u, acc, yb0, yb1, yb2, nullptr);
    feval_kernel<1><<<grid, 512, 0, stream>>>(yb0, yb1, yb2, th0, th1, th2, bias,
                                              bt, s, u, acc, ya0, ya1, ya2, nullptr);
    feval_kernel<2><<<grid, 512, 0, stream>>>(ya0, ya1, ya2, th0, th1, th2, bias,
                                              bt, s, u, acc, yb0, yb1, yb2, nullptr);
    feval_kernel<3><<<grid, 512, 0, stream>>>(yb0, yb1, yb2, th0, th1, th2, bias,
                                              bt, s, u, acc, ya0, ya1, ya2, unext);
  }
}